// Round 5
// baseline (30406.342 us; speedup 1.0000x reference)
//
#include <hip/hip_runtime.h>
#include <hip/hip_bf16.h>

#define T_STEPS 512
#define BATCH   256
#define HID     100
#define GATES   400   // 4*H
#define BT      (BATCH * T_STEPS)

__device__ __forceinline__ float sigm_f(float x) {
    return 1.f / (1.f + __expf(-x));
}

__device__ __forceinline__ float tanh_f(float x) {
    float ax = fabsf(x);
    float t  = __expf(-2.f * ax);
    float r  = (1.f - t) / (1.f + t);
    return copysignf(r, x);
}

// ---------------------------------------------------------------------------
// xg GEMM v2: A streamed from GLOBAL (per-thread row pointers, L1/L2-served,
// 16-lane address dedup), W staged in LDS (BK=100 -> 51.2 KB, one stage per
// k-tile). 8x8 microtile, BM=128, BN=128 (400 padded to 512).
// LDS per kk-quad: 8 b128/wave (was 16) -> VALU-bound.
// ---------------------------------------------------------------------------
template <int K, bool GATHER>
__global__ __launch_bounds__(256) void xg_gemm(
    const float* __restrict__ A, const int* __restrict__ idx,
    const float* __restrict__ W, const float* __restrict__ b1,
    const float* __restrict__ b2, float* __restrict__ out)
{
    constexpr int BK = (K % 100 == 0) ? 100 : 20;  // 300->100, 100->100
    __shared__ float Bs[128][BK];
    __shared__ int   idx_s[128];

    const int tid  = threadIdx.x;
    const int tx   = tid & 15;
    const int ty   = tid >> 4;
    const int row0 = blockIdx.x * 128;
    const int col0 = blockIdx.y * 128;

    if (GATHER && tid < 128) idx_s[tid] = idx[row0 + tid];
    __syncthreads();

    // per-thread A row pointers (8 rows: ty + 16*r), advance 16B per kk-quad
    const float* aptr[8];
#pragma unroll
    for (int r = 0; r < 8; ++r) {
        int row = row0 + ty + 16 * r;
        int src = GATHER ? idx_s[ty + 16 * r] : row;
        aptr[r] = A + (size_t)src * K;
    }

    float acc[8][8];
#pragma unroll
    for (int r = 0; r < 8; ++r)
#pragma unroll
        for (int j = 0; j < 8; ++j) acc[r][j] = 0.f;

#pragma unroll 1
    for (int k0 = 0; k0 < K; k0 += BK) {
        __syncthreads();
        // stage W tile: 128 gate-rows x BK floats, zero-fill rows >= 400
        for (int e = tid; e < 128 * (BK / 4); e += 256) {
            int r = e / (BK / 4), q = e % (BK / 4);
            int wrow = col0 + r;
            float4 v = make_float4(0.f, 0.f, 0.f, 0.f);
            if (wrow < GATES)
                v = *(const float4*)(W + (size_t)wrow * K + k0 + q * 4);
            *(float4*)(&Bs[r][q * 4]) = v;
        }
        __syncthreads();

#pragma unroll
        for (int kk = 0; kk < BK; kk += 4) {
            float4 a4[8];
#pragma unroll
            for (int r = 0; r < 8; ++r) {
                a4[r] = *(const float4*)(aptr[r]);
                aptr[r] += 4;
            }
#pragma unroll
            for (int j = 0; j < 8; ++j) {
                float4 b4 = *(const float4*)(&Bs[tx + 16 * j][kk]);
#pragma unroll
                for (int r = 0; r < 8; ++r) {
                    acc[r][j] += a4[r].x * b4.x + a4[r].y * b4.y +
                                 a4[r].z * b4.z + a4[r].w * b4.w;
                }
            }
        }
    }

    // epilogue: bias + guarded store
#pragma unroll
    for (int r = 0; r < 8; ++r) {
        int row = row0 + ty + 16 * r;
#pragma unroll
        for (int j = 0; j < 8; ++j) {
            int col = col0 + tx + 16 * j;
            if (col < GATES)
                out[(size_t)row * GATES + col] = acc[r][j] + b1[col] + b2[col];
        }
    }
}

// ---------------------------------------------------------------------------
// Recurrent scan v2: one block per batch, 256 threads, threads t<200 own TWO
// gate rows (t and t+200: i&g for t<100, f&o for t>=100) -> each h4 LDS read
// feeds 8 FMAs (was 4). w0+w1 = 200 VGPR.
// ---------------------------------------------------------------------------
__global__ __launch_bounds__(256) void lstm_recur(
    const float* __restrict__ xg,    // [B, T, 400]
    const float* __restrict__ w_hh,  // [400, 100]
    const int*   __restrict__ lengths,
    float* __restrict__ hs)          // [B, T, 100]
{
    const int b = blockIdx.x;
    const int t_id = threadIdx.x;
    const bool active = (t_id < 200);
    const int g0 = t_id;          // i (t<100) or f (t>=100)
    const int g1 = t_id + 200;    // g (t<100) or o (t>=100)

    __shared__ float h_s[HID];
    __shared__ float gate_s[GATES];

    float w0[HID], w1[HID];
    if (active) {
#pragma unroll
        for (int k = 0; k < HID; k += 4) {
            float4 u = *(const float4*)(w_hh + (size_t)g0 * HID + k);
            w0[k] = u.x; w0[k + 1] = u.y; w0[k + 2] = u.z; w0[k + 3] = u.w;
            float4 v = *(const float4*)(w_hh + (size_t)g1 * HID + k);
            w1[k] = v.x; w1[k + 1] = v.y; w1[k + 2] = v.z; w1[k + 3] = v.w;
        }
    }
    if (t_id < HID) h_s[t_id] = 0.f;
    float c_reg = 0.f;
    float h_reg = 0.f;

    const int len = lengths[b];
    const float* xgb = xg + (size_t)b * T_STEPS * GATES;
    float*       hsb = hs + (size_t)b * T_STEPS * HID;

    float xg0 = active ? xgb[g0] : 0.f;
    float xg1 = active ? xgb[g1] : 0.f;
    __syncthreads();

    for (int t = 0; t < T_STEPS; ++t) {
        // prefetch next step's xg
        float xgn0 = 0.f, xgn1 = 0.f;
        if (active && t + 1 < T_STEPS) {
            xgn0 = xgb[(size_t)(t + 1) * GATES + g0];
            xgn1 = xgb[(size_t)(t + 1) * GATES + g1];
        }

        if (active) {
            float s00 = 0.f, s01 = 0.f, s02 = 0.f, s03 = 0.f;
            float s10 = 0.f, s11 = 0.f, s12 = 0.f, s13 = 0.f;
#pragma unroll
            for (int k = 0; k < HID; k += 4) {
                float4 h4 = *(const float4*)(&h_s[k]);
                s00 += w0[k]     * h4.x;
                s01 += w0[k + 1] * h4.y;
                s02 += w0[k + 2] * h4.z;
                s03 += w0[k + 3] * h4.w;
                s10 += w1[k]     * h4.x;
                s11 += w1[k + 1] * h4.y;
                s12 += w1[k + 2] * h4.z;
                s13 += w1[k + 3] * h4.w;
            }
            float pre0 = xg0 + ((s00 + s01) + (s02 + s03));
            float pre1 = xg1 + ((s10 + s11) + (s12 + s13));
            // g0: i or f -> sigmoid. g1: g (t<100) -> tanh, o (t>=100) -> sigmoid
            gate_s[g0] = sigm_f(pre0);
            gate_s[g1] = (t_id < 100) ? tanh_f(pre1) : sigm_f(pre1);
        }
        __syncthreads();
        if (t_id < HID) {
            float iv = gate_s[t_id];
            float fv = gate_s[HID + t_id];
            float gv = gate_s[2 * HID + t_id];
            float ov = gate_s[3 * HID + t_id];
            float c_new = fv * c_reg + iv * gv;
            float h_new = ov * tanh_f(c_new);
            bool m = (t < len);
            c_reg = m ? c_new : c_reg;
            h_reg = m ? h_new : h_reg;
            h_s[t_id] = h_reg;
            hsb[(size_t)t * HID + t_id] = h_reg;
        }
        xg0 = xgn0;
        xg1 = xgn1;
        __syncthreads();
    }
}

// ---------------------------------------------------------------------------
// Final linear head
// ---------------------------------------------------------------------------
__global__ __launch_bounds__(64) void fc_kernel(
    const float* __restrict__ hs, const float* __restrict__ w_fc,
    const float* __restrict__ b_fc, float* __restrict__ out)
{
    int tid = blockIdx.x * 64 + threadIdx.x;
    if (tid >= BATCH * 3) return;
    int b = tid / 3, o = tid % 3;
    const float* h = hs + ((size_t)b * T_STEPS + (T_STEPS - 1)) * HID;
    float acc = b_fc[o];
    for (int j = 0; j < HID; ++j) acc += h[j] * w_fc[o * HID + j];
    out[b * 3 + o] = acc;
}

extern "C" void kernel_launch(void* const* d_in, const int* in_sizes, int n_in,
                              void* d_out, int out_size, void* d_ws, size_t ws_size,
                              hipStream_t stream)
{
    const int*   x       = (const int*)  d_in[0];
    const int*   lengths = (const int*)  d_in[1];
    const float* emb     = (const float*)d_in[2];
    const float* w_ih0   = (const float*)d_in[3];
    const float* w_hh0   = (const float*)d_in[4];
    const float* b_ih0   = (const float*)d_in[5];
    const float* b_hh0   = (const float*)d_in[6];
    const float* w_ih1   = (const float*)d_in[7];
    const float* w_hh1   = (const float*)d_in[8];
    const float* b_ih1   = (const float*)d_in[9];
    const float* b_hh1   = (const float*)d_in[10];
    const float* w_ih2   = (const float*)d_in[11];
    const float* w_hh2   = (const float*)d_in[12];
    const float* b_ih2   = (const float*)d_in[13];
    const float* b_hh2   = (const float*)d_in[14];
    const float* w_fc    = (const float*)d_in[15];
    const float* b_fc    = (const float*)d_in[16];
    float* out = (float*)d_out;

    float* xg = (float*)d_ws;                  // [BT, 400]  ~210 MB
    float* hs = xg + (size_t)BT * GATES;       // [BT, 100]  ~52 MB

    dim3 ggrid(BT / 128, 4);

    // Layer 0: embedding gather fused into A-stage, K=300
    xg_gemm<300, true><<<ggrid, 256, 0, stream>>>(emb, x, w_ih0, b_ih0, b_hh0, xg);
    lstm_recur<<<BATCH, 256, 0, stream>>>(xg, w_hh0, lengths, hs);

    // Layer 1
    xg_gemm<100, false><<<ggrid, 256, 0, stream>>>(hs, nullptr, w_ih1, b_ih1, b_hh1, xg);
    lstm_recur<<<BATCH, 256, 0, stream>>>(xg, w_hh1, lengths, hs);

    // Layer 2
    xg_gemm<100, false><<<ggrid, 256, 0, stream>>>(hs, nullptr, w_ih2, b_ih2, b_hh2, xg);
    lstm_recur<<<BATCH, 256, 0, stream>>>(xg, w_hh2, lengths, hs);

    // Head
    fc_kernel<<<(BATCH * 3 + 63) / 64, 64, 0, stream>>>(hs, w_fc, b_fc, out);
}

// Round 6
// 3941.730 us; speedup vs baseline: 7.7140x; 7.7140x over previous
//
#include <hip/hip_runtime.h>
#include <hip/hip_bf16.h>

#define T_STEPS 512
#define BATCH   256
#define HID     100
#define GATES   400   // 4*H
#define BT      (BATCH * T_STEPS)

__device__ __forceinline__ float sigm_f(float x) {
    return 1.f / (1.f + __expf(-x));
}

__device__ __forceinline__ float tanh_f(float x) {
    float ax = fabsf(x);
    float t  = __expf(-2.f * ax);
    float r  = (1.f - t) / (1.f + t);
    return copysignf(r, x);
}

// ---------------------------------------------------------------------------
// xg GEMM v3: round-4 structure (BM=128, BN=128, BK=20, 8x8 microtile,
// LDS-staged A and W) + double-buffered staging (stage k0+20 while computing
// k0 -> global-load latency hidden under FMAs) + swapped grid (blockIdx.x =
// col-tile so the 4 blocks sharing the same A rows are dispatch-adjacent and
// A re-reads hit L2 instead of HBM).
// NO min-waves hint (rounds 1-3: any cap below the live set spills acc).
// ---------------------------------------------------------------------------
template <int K, bool GATHER>
__global__ __launch_bounds__(256) void xg_gemm(
    const float* __restrict__ A, const int* __restrict__ idx,
    const float* __restrict__ W, const float* __restrict__ b1,
    const float* __restrict__ b2, float* __restrict__ out)
{
    __shared__ float As[2][128][20];
    __shared__ float Bs[2][128][20];
    __shared__ int   idx_s[128];

    const int tid  = threadIdx.x;
    const int tx   = tid & 15;
    const int ty   = tid >> 4;
    const int col0 = blockIdx.x * 128;   // col-tile fastest -> A shared via L2
    const int row0 = blockIdx.y * 128;

    if (GATHER) {
        if (tid < 128) idx_s[tid] = idx[row0 + tid];
        __syncthreads();
    }

    // initial stage: k0 = 0 into buffer 0
    for (int e = tid; e < 640; e += 256) {
        int r = e / 5, kq = e % 5;
        int src = GATHER ? idx_s[r] : (row0 + r);
        *(float4*)(&As[0][r][kq * 4]) =
            *(const float4*)(A + (size_t)src * K + kq * 4);
    }
    for (int e = tid; e < 640; e += 256) {
        int r = e / 5, kq = e % 5;
        int wrow = col0 + r;
        float4 v = make_float4(0.f, 0.f, 0.f, 0.f);
        if (wrow < GATES)
            v = *(const float4*)(W + (size_t)wrow * K + kq * 4);
        *(float4*)(&Bs[0][r][kq * 4]) = v;
    }

    float acc[8][8];
#pragma unroll
    for (int r = 0; r < 8; ++r)
#pragma unroll
        for (int j = 0; j < 8; ++j) acc[r][j] = 0.f;

    int cur = 0;
#pragma unroll 1
    for (int k0 = 0; k0 < K; k0 += 20) {
        __syncthreads();   // buf[cur] staged; buf[cur^1] free for next stage

        const int kn = k0 + 20;
        if (kn < K) {
            // stage next k-tile into the other buffer; overlaps compute below
            for (int e = tid; e < 640; e += 256) {
                int r = e / 5, kq = e % 5;
                int src = GATHER ? idx_s[r] : (row0 + r);
                *(float4*)(&As[cur ^ 1][r][kq * 4]) =
                    *(const float4*)(A + (size_t)src * K + kn + kq * 4);
            }
            for (int e = tid; e < 640; e += 256) {
                int r = e / 5, kq = e % 5;
                int wrow = col0 + r;
                float4 v = make_float4(0.f, 0.f, 0.f, 0.f);
                if (wrow < GATES)
                    v = *(const float4*)(W + (size_t)wrow * K + kn + kq * 4);
                *(float4*)(&Bs[cur ^ 1][r][kq * 4]) = v;
            }
        }

#pragma unroll
        for (int kk = 0; kk < 20; kk += 4) {
            float4 a4[8];
#pragma unroll
            for (int r = 0; r < 8; ++r)
                a4[r] = *(const float4*)(&As[cur][ty + 16 * r][kk]);
#pragma unroll
            for (int j = 0; j < 8; ++j) {
                float4 b4 = *(const float4*)(&Bs[cur][tx + 16 * j][kk]);
#pragma unroll
                for (int r = 0; r < 8; ++r) {
                    acc[r][j] += a4[r].x * b4.x + a4[r].y * b4.y +
                                 a4[r].z * b4.z + a4[r].w * b4.w;
                }
            }
        }
        cur ^= 1;
    }

    // epilogue: bias + guarded store
#pragma unroll
    for (int r = 0; r < 8; ++r) {
        int row = row0 + ty + 16 * r;
#pragma unroll
        for (int j = 0; j < 8; ++j) {
            int col = col0 + tx + 16 * j;
            if (col < GATES)
                out[(size_t)row * GATES + col] = acc[r][j] + b1[col] + b2[col];
        }
    }
}

// ---------------------------------------------------------------------------
// Recurrent scan: one block per batch, 256 threads, threads t<200 own TWO
// gate rows (t and t+200) -> each h4 LDS broadcast read feeds 8 FMAs.
// xg prefetched 2 steps deep (~1200 cyc of cover > ~900 cyc HBM latency).
// ---------------------------------------------------------------------------
__global__ __launch_bounds__(256) void lstm_recur(
    const float* __restrict__ xg,    // [B, T, 400]
    const float* __restrict__ w_hh,  // [400, 100]
    const int*   __restrict__ lengths,
    float* __restrict__ hs)          // [B, T, 100]
{
    const int b = blockIdx.x;
    const int t_id = threadIdx.x;
    const bool active = (t_id < 200);
    const int g0 = t_id;          // i (t<100) or f (t>=100)
    const int g1 = t_id + 200;    // g (t<100) or o (t>=100)

    __shared__ float h_s[HID];
    __shared__ float gate_s[GATES];

    float w0[HID], w1[HID];
    if (active) {
#pragma unroll
        for (int k = 0; k < HID; k += 4) {
            float4 u = *(const float4*)(w_hh + (size_t)g0 * HID + k);
            w0[k] = u.x; w0[k + 1] = u.y; w0[k + 2] = u.z; w0[k + 3] = u.w;
            float4 v = *(const float4*)(w_hh + (size_t)g1 * HID + k);
            w1[k] = v.x; w1[k + 1] = v.y; w1[k + 2] = v.z; w1[k + 3] = v.w;
        }
    }
    if (t_id < HID) h_s[t_id] = 0.f;
    float c_reg = 0.f;
    float h_reg = 0.f;

    const int len = lengths[b];
    const float* xgb = xg + (size_t)b * T_STEPS * GATES;
    float*       hsb = hs + (size_t)b * T_STEPS * HID;

    // 2-deep prefetch pipeline: xc = step t, xn = step t+1
    float xc0 = 0.f, xc1 = 0.f, xn0 = 0.f, xn1 = 0.f;
    if (active) {
        xc0 = xgb[g0];
        xc1 = xgb[g1];
        xn0 = xgb[GATES + g0];
        xn1 = xgb[GATES + g1];
    }
    __syncthreads();

    for (int t = 0; t < T_STEPS; ++t) {
        // issue loads for step t+2
        float xf0 = 0.f, xf1 = 0.f;
        if (active && t + 2 < T_STEPS) {
            xf0 = xgb[(size_t)(t + 2) * GATES + g0];
            xf1 = xgb[(size_t)(t + 2) * GATES + g1];
        }

        if (active) {
            float s00 = 0.f, s01 = 0.f, s02 = 0.f, s03 = 0.f;
            float s10 = 0.f, s11 = 0.f, s12 = 0.f, s13 = 0.f;
#pragma unroll
            for (int k = 0; k < HID; k += 4) {
                float4 h4 = *(const float4*)(&h_s[k]);
                s00 += w0[k]     * h4.x;
                s01 += w0[k + 1] * h4.y;
                s02 += w0[k + 2] * h4.z;
                s03 += w0[k + 3] * h4.w;
                s10 += w1[k]     * h4.x;
                s11 += w1[k + 1] * h4.y;
                s12 += w1[k + 2] * h4.z;
                s13 += w1[k + 3] * h4.w;
            }
            float pre0 = xc0 + ((s00 + s01) + (s02 + s03));
            float pre1 = xc1 + ((s10 + s11) + (s12 + s13));
            gate_s[g0] = sigm_f(pre0);
            gate_s[g1] = (t_id < 100) ? tanh_f(pre1) : sigm_f(pre1);
        }
        __syncthreads();
        if (t_id < HID) {
            float iv = gate_s[t_id];
            float fv = gate_s[HID + t_id];
            float gv = gate_s[2 * HID + t_id];
            float ov = gate_s[3 * HID + t_id];
            float c_new = fv * c_reg + iv * gv;
            float h_new = ov * tanh_f(c_new);
            bool m = (t < len);
            c_reg = m ? c_new : c_reg;
            h_reg = m ? h_new : h_reg;
            h_s[t_id] = h_reg;
            hsb[(size_t)t * HID + t_id] = h_reg;
        }
        xc0 = xn0; xc1 = xn1;
        xn0 = xf0; xn1 = xf1;
        __syncthreads();
    }
}

// ---------------------------------------------------------------------------
// Final linear head
// ---------------------------------------------------------------------------
__global__ __launch_bounds__(64) void fc_kernel(
    const float* __restrict__ hs, const float* __restrict__ w_fc,
    const float* __restrict__ b_fc, float* __restrict__ out)
{
    int tid = blockIdx.x * 64 + threadIdx.x;
    if (tid >= BATCH * 3) return;
    int b = tid / 3, o = tid % 3;
    const float* h = hs + ((size_t)b * T_STEPS + (T_STEPS - 1)) * HID;
    float acc = b_fc[o];
    for (int j = 0; j < HID; ++j) acc += h[j] * w_fc[o * HID + j];
    out[b * 3 + o] = acc;
}

extern "C" void kernel_launch(void* const* d_in, const int* in_sizes, int n_in,
                              void* d_out, int out_size, void* d_ws, size_t ws_size,
                              hipStream_t stream)
{
    const int*   x       = (const int*)  d_in[0];
    const int*   lengths = (const int*)  d_in[1];
    const float* emb     = (const float*)d_in[2];
    const float* w_ih0   = (const float*)d_in[3];
    const float* w_hh0   = (const float*)d_in[4];
    const float* b_ih0   = (const float*)d_in[5];
    const float* b_hh0   = (const float*)d_in[6];
    const float* w_ih1   = (const float*)d_in[7];
    const float* w_hh1   = (const float*)d_in[8];
    const float* b_ih1   = (const float*)d_in[9];
    const float* b_hh1   = (const float*)d_in[10];
    const float* w_ih2   = (const float*)d_in[11];
    const float* w_hh2   = (const float*)d_in[12];
    const float* b_ih2   = (const float*)d_in[13];
    const float* b_hh2   = (const float*)d_in[14];
    const float* w_fc    = (const float*)d_in[15];
    const float* b_fc    = (const float*)d_in[16];
    float* out = (float*)d_out;

    float* xg = (float*)d_ws;                  // [BT, 400]  ~210 MB
    float* hs = xg + (size_t)BT * GATES;       // [BT, 100]  ~52 MB

    dim3 ggrid(4, BT / 128);   // x = col-tile (fast), y = row-tile

    // Layer 0: embedding gather fused into A-stage, K=300
    xg_gemm<300, true><<<ggrid, 256, 0, stream>>>(emb, x, w_ih0, b_ih0, b_hh0, xg);
    lstm_recur<<<BATCH, 256, 0, stream>>>(xg, w_hh0, lengths, hs);

    // Layer 1
    xg_gemm<100, false><<<ggrid, 256, 0, stream>>>(hs, nullptr, w_ih1, b_ih1, b_hh1, xg);
    lstm_recur<<<BATCH, 256, 0, stream>>>(xg, w_hh1, lengths, hs);

    // Layer 2
    xg_gemm<100, false><<<ggrid, 256, 0, stream>>>(hs, nullptr, w_ih2, b_ih2, b_hh2, xg);
    lstm_recur<<<BATCH, 256, 0, stream>>>(xg, w_hh2, lengths, hs);

    // Head
    fc_kernel<<<(BATCH * 3 + 63) / 64, 64, 0, stream>>>(hs, w_fc, b_fc, out);
}

// Round 7
// 3056.072 us; speedup vs baseline: 9.9495x; 1.2898x over previous
//
#include <hip/hip_runtime.h>
#include <hip/hip_bf16.h>

#define T_STEPS 512
#define BATCH   256
#define HID     100
#define GATES   400   // 4*H
#define BT      (BATCH * T_STEPS)

__device__ __forceinline__ float sigm_f(float x) {
    return 1.f / (1.f + __expf(-x));
}

__device__ __forceinline__ float tanh_f(float x) {
    float ax = fabsf(x);
    float t  = __expf(-2.f * ax);
    float r  = (1.f - t) / (1.f + t);
    return copysignf(r, x);
}

// ---------------------------------------------------------------------------
// xg GEMM (unchanged from round 6): BM=128, BN=128, BK=20, 8x8 microtile,
// double-buffered LDS staging, col-tile-fastest grid for L2 reuse of A.
// NO min-waves hint (rounds 1-3: any cap below the live set spills acc).
// ---------------------------------------------------------------------------
template <int K, bool GATHER>
__global__ __launch_bounds__(256) void xg_gemm(
    const float* __restrict__ A, const int* __restrict__ idx,
    const float* __restrict__ W, const float* __restrict__ b1,
    const float* __restrict__ b2, float* __restrict__ out)
{
    __shared__ float As[2][128][20];
    __shared__ float Bs[2][128][20];
    __shared__ int   idx_s[128];

    const int tid  = threadIdx.x;
    const int tx   = tid & 15;
    const int ty   = tid >> 4;
    const int col0 = blockIdx.x * 128;
    const int row0 = blockIdx.y * 128;

    if (GATHER) {
        if (tid < 128) idx_s[tid] = idx[row0 + tid];
        __syncthreads();
    }

    for (int e = tid; e < 640; e += 256) {
        int r = e / 5, kq = e % 5;
        int src = GATHER ? idx_s[r] : (row0 + r);
        *(float4*)(&As[0][r][kq * 4]) =
            *(const float4*)(A + (size_t)src * K + kq * 4);
    }
    for (int e = tid; e < 640; e += 256) {
        int r = e / 5, kq = e % 5;
        int wrow = col0 + r;
        float4 v = make_float4(0.f, 0.f, 0.f, 0.f);
        if (wrow < GATES)
            v = *(const float4*)(W + (size_t)wrow * K + kq * 4);
        *(float4*)(&Bs[0][r][kq * 4]) = v;
    }

    float acc[8][8];
#pragma unroll
    for (int r = 0; r < 8; ++r)
#pragma unroll
        for (int j = 0; j < 8; ++j) acc[r][j] = 0.f;

    int cur = 0;
#pragma unroll 1
    for (int k0 = 0; k0 < K; k0 += 20) {
        __syncthreads();

        const int kn = k0 + 20;
        if (kn < K) {
            for (int e = tid; e < 640; e += 256) {
                int r = e / 5, kq = e % 5;
                int src = GATHER ? idx_s[r] : (row0 + r);
                *(float4*)(&As[cur ^ 1][r][kq * 4]) =
                    *(const float4*)(A + (size_t)src * K + kn + kq * 4);
            }
            for (int e = tid; e < 640; e += 256) {
                int r = e / 5, kq = e % 5;
                int wrow = col0 + r;
                float4 v = make_float4(0.f, 0.f, 0.f, 0.f);
                if (wrow < GATES)
                    v = *(const float4*)(W + (size_t)wrow * K + kn + kq * 4);
                *(float4*)(&Bs[cur ^ 1][r][kq * 4]) = v;
            }
        }

#pragma unroll
        for (int kk = 0; kk < 20; kk += 4) {
            float4 a4[8];
#pragma unroll
            for (int r = 0; r < 8; ++r)
                a4[r] = *(const float4*)(&As[cur][ty + 16 * r][kk]);
#pragma unroll
            for (int j = 0; j < 8; ++j) {
                float4 b4 = *(const float4*)(&Bs[cur][tx + 16 * j][kk]);
#pragma unroll
                for (int r = 0; r < 8; ++r) {
                    acc[r][j] += a4[r].x * b4.x + a4[r].y * b4.y +
                                 a4[r].z * b4.z + a4[r].w * b4.w;
                }
            }
        }
        cur ^= 1;
    }

#pragma unroll
    for (int r = 0; r < 8; ++r) {
        int row = row0 + ty + 16 * r;
#pragma unroll
        for (int j = 0; j < 8; ++j) {
            int col = col0 + tx + 16 * j;
            if (col < GATES)
                out[(size_t)row * GATES + col] = acc[r][j] + b1[col] + b2[col];
        }
    }
}

// ---------------------------------------------------------------------------
// Recurrent scan v3 (quad-gate layout):
//   thread 4j+gt owns gate row gt*100+j  (gt: 0=i,1=f,2=g,3=o)
//   - gates of hidden j are lanes 4j..4j+3 -> activation exchange via
//     __shfl_xor (quad), c/h computed redundantly in all 4 lanes
//   - ONE barrier per step (h double-buffered in LDS)
//   - xg staged into LDS in 32-step chunks (51.2 KB), one latency stall
//     per 32 steps instead of per step
// ---------------------------------------------------------------------------
__global__ __launch_bounds__(448) void lstm_recur(
    const float* __restrict__ xg,    // [B, T, 400]
    const float* __restrict__ w_hh,  // [400, 100]
    const int*   __restrict__ lengths,
    float* __restrict__ hs)          // [B, T, 100]
{
    const int b   = blockIdx.x;
    const int tid = threadIdx.x;
    const bool active = (tid < 400);
    const int j    = tid >> 2;      // hidden index (active: 0..99)
    const int gt   = tid & 3;       // gate type
    const int grow = gt * HID + j;  // gate row / xg column

    __shared__ float xg_s[32 * GATES];   // 51.2 KB, one 32-step chunk
    __shared__ float h_s[2][HID];

    float w[HID];
    if (active) {
        const float* wr = w_hh + (size_t)grow * HID;
#pragma unroll
        for (int k = 0; k < HID; k += 4) {
            float4 u = *(const float4*)(wr + k);
            w[k] = u.x; w[k + 1] = u.y; w[k + 2] = u.z; w[k + 3] = u.w;
        }
    }
    if (active && gt == 0) h_s[0][j] = 0.f;

    float c_reg = 0.f, h_reg = 0.f;
    const int len = lengths[b];
    const float* xgb = xg + (size_t)b * T_STEPS * GATES;
    float*       hsb = hs + (size_t)b * T_STEPS * HID;

    const bool is0 = (gt == 0), is1 = (gt == 1), is2 = (gt == 2);

    for (int t = 0; t < T_STEPS; ++t) {
        if ((t & 31) == 0) {
            // stage xg[t .. t+32) (end-of-step barrier of t-1 guarantees
            // prior chunk's reads are done)
            const float4* src = (const float4*)(xgb + (size_t)t * GATES);
            float4*       dst = (float4*)xg_s;
            for (int i = tid; i < 32 * GATES / 4; i += 448)
                dst[i] = src[i];
            __syncthreads();
        }

        float pre = 0.f;
        if (active) {
            float s0 = 0.f, s1 = 0.f, s2 = 0.f, s3 = 0.f;
            const float* hb = h_s[t & 1];
#pragma unroll
            for (int k = 0; k < HID; k += 4) {
                float4 h4 = *(const float4*)(hb + k);
                s0 += w[k]     * h4.x;
                s1 += w[k + 1] * h4.y;
                s2 += w[k + 2] * h4.z;
                s3 += w[k + 3] * h4.w;
            }
            pre = xg_s[(t & 31) * GATES + grow] + ((s0 + s1) + (s2 + s3));
        }
        // own activation (tanh only for gate type 2)
        float p0 = is2 ? tanh_f(pre) : sigm_f(pre);
        // quad exchange: p_m = activation of gate (gt ^ m)
        float p1 = __shfl_xor(p0, 1);
        float p2 = __shfl_xor(p0, 2);
        float p3 = __shfl_xor(p1, 2);
        // act of gate k = p[gt ^ k]
        float iv = is0 ? p0 : is1 ? p1 : is2 ? p2 : p3;
        float fv = is0 ? p1 : is1 ? p0 : is2 ? p3 : p2;
        float gv = is0 ? p2 : is1 ? p3 : is2 ? p0 : p1;
        float ov = is0 ? p3 : is1 ? p2 : is2 ? p1 : p0;

        float c_new = fv * c_reg + iv * gv;
        float h_new = ov * tanh_f(c_new);
        bool  m     = (t < len);
        c_reg = m ? c_new : c_reg;
        h_reg = m ? h_new : h_reg;

        if (active && gt == 0) {
            h_s[(t & 1) ^ 1][j] = h_reg;
            hsb[(size_t)t * HID + j] = h_reg;
        }
        __syncthreads();
    }
}

// ---------------------------------------------------------------------------
// Final linear head
// ---------------------------------------------------------------------------
__global__ __launch_bounds__(64) void fc_kernel(
    const float* __restrict__ hs, const float* __restrict__ w_fc,
    const float* __restrict__ b_fc, float* __restrict__ out)
{
    int tid = blockIdx.x * 64 + threadIdx.x;
    if (tid >= BATCH * 3) return;
    int b = tid / 3, o = tid % 3;
    const float* h = hs + ((size_t)b * T_STEPS + (T_STEPS - 1)) * HID;
    float acc = b_fc[o];
    for (int j = 0; j < HID; ++j) acc += h[j] * w_fc[o * HID + j];
    out[b * 3 + o] = acc;
}

extern "C" void kernel_launch(void* const* d_in, const int* in_sizes, int n_in,
                              void* d_out, int out_size, void* d_ws, size_t ws_size,
                              hipStream_t stream)
{
    const int*   x       = (const int*)  d_in[0];
    const int*   lengths = (const int*)  d_in[1];
    const float* emb     = (const float*)d_in[2];
    const float* w_ih0   = (const float*)d_in[3];
    const float* w_hh0   = (const float*)d_in[4];
    const float* b_ih0   = (const float*)d_in[5];
    const float* b_hh0   = (const float*)d_in[6];
    const float* w_ih1   = (const float*)d_in[7];
    const float* w_hh1   = (const float*)d_in[8];
    const float* b_ih1   = (const float*)d_in[9];
    const float* b_hh1   = (const float*)d_in[10];
    const float* w_ih2   = (const float*)d_in[11];
    const float* w_hh2   = (const float*)d_in[12];
    const float* b_ih2   = (const float*)d_in[13];
    const float* b_hh2   = (const float*)d_in[14];
    const float* w_fc    = (const float*)d_in[15];
    const float* b_fc    = (const float*)d_in[16];
    float* out = (float*)d_out;

    float* xg = (float*)d_ws;                  // [BT, 400]  ~210 MB
    float* hs = xg + (size_t)BT * GATES;       // [BT, 100]  ~52 MB

    dim3 ggrid(4, BT / 128);   // x = col-tile (fast), y = row-tile

    // Layer 0: embedding gather fused into A-stage, K=300
    xg_gemm<300, true><<<ggrid, 256, 0, stream>>>(emb, x, w_ih0, b_ih0, b_hh0, xg);
    lstm_recur<<<BATCH, 448, 0, stream>>>(xg, w_hh0, lengths, hs);

    // Layer 1
    xg_gemm<100, false><<<ggrid, 256, 0, stream>>>(hs, nullptr, w_ih1, b_ih1, b_hh1, xg);
    lstm_recur<<<BATCH, 448, 0, stream>>>(xg, w_hh1, lengths, hs);

    // Layer 2
    xg_gemm<100, false><<<ggrid, 256, 0, stream>>>(hs, nullptr, w_ih2, b_ih2, b_hh2, xg);
    lstm_recur<<<BATCH, 448, 0, stream>>>(xg, w_hh2, lengths, hs);

    // Head
    fc_kernel<<<(BATCH * 3 + 63) / 64, 64, 0, stream>>>(hs, w_fc, b_fc, out);
}